// Round 12
// baseline (602.064 us; speedup 1.0000x reference)
//
#include <hip/hip_runtime.h>

#define NRAD 20
#define MNODE 8

typedef unsigned short ushort_t;
typedef unsigned int uint_t;

struct U3 { uint_t a, b, c; };   // 12B interleaved gather payload

__device__ __forceinline__ float rdlane(float v, int l)
{
    return __uint_as_float(__builtin_amdgcn_readlane(__float_as_uint(v), l));
}

__device__ __forceinline__ ushort_t f2bf(float f)
{
    uint_t u = __float_as_uint(f);
    u += 0x7fff + ((u >> 16) & 1);   // round-to-nearest-even
    return (ushort_t)(u >> 16);
}

__device__ __forceinline__ uint_t pack2bf(float a, float b)
{
    return (uint_t)f2bf(a) | ((uint_t)f2bf(b) << 16);
}

__device__ __forceinline__ float bflo(uint_t w) { return __uint_as_float(w << 16); }
__device__ __forceinline__ float bfhi(uint_t w) { return __uint_as_float(w & 0xffff0000u); }
__device__ __forceinline__ float bf2f(ushort_t h) { return __uint_as_float(((uint_t)h) << 16); }

// ---------------------------------------------------------------------------
// Detect edge_index storage: int32 (flag=1) vs int64 (flag=0).
// ---------------------------------------------------------------------------
__global__ void detect_idx_kernel(const int* __restrict__ eidx, int* __restrict__ flag)
{
    int t = threadIdx.x;  // 64 threads, one wave
    unsigned long long m = __ballot(eidx[2 * t + 1] != 0);
    if (t == 0) flag[0] = (__popcll(m) > 8) ? 1 : 0;
}

// ---------------------------------------------------------------------------
// CSR build: histogram, 3-stage scan -> cur, then record-building scatter.
// ---------------------------------------------------------------------------
__global__ void hist_kernel(const int* __restrict__ eidx, const int* __restrict__ flag,
                            int* __restrict__ counts, int n_edges)
{
    int fmt32 = flag[0];
    int i0 = blockIdx.x * blockDim.x + threadIdx.x;
    int stride = gridDim.x * blockDim.x;
    if (fmt32) {
        for (int e = i0; e < n_edges; e += stride) atomicAdd(&counts[eidx[2 * e]], 1);
    } else {
        const long long* e64 = (const long long*)eidx;
        for (int e = i0; e < n_edges; e += stride) atomicAdd(&counts[(int)e64[2 * e]], 1);
    }
}

__global__ __launch_bounds__(256)
void scan1_kernel(const int* __restrict__ cnt, int* __restrict__ bsum, int n, int ch)
{
    __shared__ int red[4];
    int b = blockIdx.x, t = threadIdx.x;
    int end = min(n, (b + 1) * ch);
    int v = 0;
    for (int i = b * ch + t; i < end; i += 256) v += cnt[i];
#pragma unroll
    for (int d = 1; d < 64; d <<= 1) v += __shfl_xor(v, d, 64);
    if ((t & 63) == 0) red[t >> 6] = v;
    __syncthreads();
    if (t == 0) bsum[b] = red[0] + red[1] + red[2] + red[3];
}

__global__ __launch_bounds__(256)
void scan2_kernel(const int* __restrict__ bsum, int* __restrict__ bscan, int nb)
{
    __shared__ int wsum[4];
    int t = threadIdx.x, lane = t & 63, w = t >> 6;
    int v = (t < nb) ? bsum[t] : 0;
    int sc = v;
#pragma unroll
    for (int d = 1; d < 64; d <<= 1) {
        int u = __shfl_up(sc, (unsigned)d, 64);
        if (lane >= d) sc += u;
    }
    if (lane == 63) wsum[w] = sc;
    __syncthreads();
    int add = 0;
    for (int j = 0; j < w; j++) add += wsum[j];
    if (t < nb) bscan[t] = (sc + add) - v;
}

__global__ __launch_bounds__(256)
void scan3_kernel(const int* __restrict__ cnt, const int* __restrict__ bscan,
                  int* __restrict__ cur, int n, int ch)
{
    __shared__ int wsum[4];
    __shared__ int btot;
    int b = blockIdx.x, t = threadIdx.x, lane = t & 63, w = t >> 6;
    int end = min(n, (b + 1) * ch);
    int carry = bscan[b];
    for (int base = b * ch; base < end; base += 256) {
        int i = base + t;
        int v = (i < end) ? cnt[i] : 0;
        int sc = v;
#pragma unroll
        for (int d = 1; d < 64; d <<= 1) {
            int u = __shfl_up(sc, (unsigned)d, 64);
            if (lane >= d) sc += u;
        }
        if (lane == 63) wsum[w] = sc;
        __syncthreads();
        int add = 0;
        for (int j = 0; j < w; j++) add += wsum[j];
        if (t == 255) btot = sc + add;
        int excl = carry + (sc + add - v);
        if (i < end) cur[i] = excl;
        __syncthreads();
        carry += btot;
    }
}

// ---------------------------------------------------------------------------
// scatter_rec2: LDS-staged record build.  Block = 256 contiguous edges; rbf,
// rij, env staged via perfectly COALESCED global loads (scatter_rec's old
// 5x float4-stride-80 rbf pattern overfetched ~4x = ~256MB effective).
// rbf readback uses padded stride 21 (gcd(21,32)=1 -> conflict-free).
// Output records identical to round-11 layout:
//   {src,dst,env,r0} {r1,r2,w0,w1} {w2..w5} {w6..w9}, wi = bf16 pair.
// ---------------------------------------------------------------------------
__global__ __launch_bounds__(256)
void scatter_rec2_kernel(const int* __restrict__ eidx, const int* __restrict__ flag,
                         int* __restrict__ cur,
                         const float* __restrict__ env, const float* __restrict__ rij,
                         const float* __restrict__ rbf,
                         uint4* __restrict__ rec, int n_edges)
{
    __shared__ float s_rbf[256 * 21];    // padded
    __shared__ float s_rij[256 * 3];
    __shared__ float s_env[256];

    const int t = threadIdx.x;
    const int chunk = blockIdx.x * 256;
    const int nval = min(256, n_edges - chunk);
    if (nval <= 0) return;

    for (int i = t; i < nval * 20; i += 256) {
        int e2 = i / 20, k = i - e2 * 20;
        s_rbf[e2 * 21 + k] = rbf[(size_t)chunk * 20 + i];
    }
    for (int i = t; i < nval * 3; i += 256) s_rij[i] = rij[(size_t)chunk * 3 + i];
    for (int i = t; i < nval; i += 256)     s_env[i] = env[chunk + i];
    __syncthreads();

    if (t < nval) {
        const int e = chunk + t;
        int dst, src;
        if (flag[0]) { dst = eidx[2 * e]; src = eidx[2 * e + 1]; }
        else {
            const long long* e64 = (const long long*)eidx;
            dst = (int)e64[2 * e]; src = (int)e64[2 * e + 1];
        }
        int pos = atomicAdd(&cur[dst], 1);
        float ev = s_env[t];
        float r0 = s_rij[3 * t], r1 = s_rij[3 * t + 1], r2 = s_rij[3 * t + 2];
        const float* rb = &s_rbf[t * 21];
        uint4 qa, qb, qc, qd;
        qa.x = (uint_t)src; qa.y = (uint_t)dst;
        qa.z = __float_as_uint(ev); qa.w = __float_as_uint(r0);
        qb.x = __float_as_uint(r1); qb.y = __float_as_uint(r2);
        qb.z = pack2bf(rb[0], rb[1]);   qb.w = pack2bf(rb[2], rb[3]);
        qc.x = pack2bf(rb[4], rb[5]);   qc.y = pack2bf(rb[6], rb[7]);
        qc.z = pack2bf(rb[8], rb[9]);   qc.w = pack2bf(rb[10], rb[11]);
        qd.x = pack2bf(rb[12], rb[13]); qd.y = pack2bf(rb[14], rb[15]);
        qd.z = pack2bf(rb[16], rb[17]); qd.w = pack2bf(rb[18], rb[19]);
        size_t rp = (size_t)pos * 4;
        rec[rp] = qa; rec[rp + 1] = qb; rec[rp + 2] = qc; rec[rp + 3] = qd;
    }
}

// T2: plain index scatter (fallback when rec doesn't fit ws).
__global__ void scatter_kernel(const int* __restrict__ eidx, const int* __restrict__ flag,
                               int* __restrict__ cur, int* __restrict__ sorted, int n_edges)
{
    int fmt32 = flag[0];
    int i0 = blockIdx.x * blockDim.x + threadIdx.x;
    int stride = gridDim.x * blockDim.x;
    const long long* e64 = (const long long*)eidx;
    for (int e = i0; e < n_edges; e += stride) {
        int dst = fmt32 ? eidx[2 * e] : (int)e64[2 * e];
        int pos = atomicAdd(&cur[dst], 1);
        sorted[pos] = e;
    }
}

// ---------------------------------------------------------------------------
// Pack Ww into per-lane bf16 pair table:
// wpkp[(c*10+p)*64 + lane] = pack2bf(Ww[(c*64+lane)*20+2p], Ww[..+2p+1]).
// ---------------------------------------------------------------------------
__global__ void prep_wpkp_kernel(const float* __restrict__ Ww, uint_t* __restrict__ wpkp)
{
    int idx = blockIdx.x * 256 + threadIdx.x;
    if (idx >= 1920) return;
    int lane = idx & 63;
    int r = idx >> 6;          // 0..29 = c*10+p
    int p = r % 10;
    int c = r / 10;
    int n = c * 64 + lane;
    wpkp[idx] = pack2bf(Ww[n * 20 + 2 * p], Ww[n * 20 + 2 * p + 1]);
}

// ---------------------------------------------------------------------------
// node_mlp4: round-11 node MLP FUSED with eq_cast.  Each lane writes its full
// 12B sq payload (slots 0..5) as 3 u32 stores -> wave writes 768B contiguous,
// full-line coverage (eq_cast's old stride-12 2-byte writes partially covered
// lines; sq > L2 so partial lines risked write amplification).  Rounding of
// every value identical to the separate kernels.
// ---------------------------------------------------------------------------
__global__ __launch_bounds__(256)
void node_mlp4(const float* __restrict__ node, const float* __restrict__ eq,
               const float* __restrict__ Ws, const float* __restrict__ bs,
               const float* __restrict__ Wphi, const float* __restrict__ bphi,
               ushort_t* __restrict__ sq, int n_nodes)
{
    __shared__ float WsT[64 * 64];    // [k][j] = Ws[j][k]
    __shared__ float WphiT[64 * 192]; // [k][j] = Wphi[j][k]
    const int t = threadIdx.x;
    for (int i = t; i < 64 * 64; i += 256) {
        int j = i >> 6, k = i & 63;
        WsT[k * 64 + j] = Ws[i];
    }
    for (int i = t; i < 192 * 64; i += 256) {
        int j = i >> 6, k = i & 63;
        WphiT[k * 192 + j] = Wphi[i];
    }
    __syncthreads();

    const int lane = t & 63;
    const int wave = t >> 6;
    const int gw = blockIdx.x * 4 + wave;
    const int nw = gridDim.x * 4;
    const float bsc = bs[lane];
    const float bp0 = bphi[lane], bp1 = bphi[64 + lane], bp2 = bphi[128 + lane];

    for (int n0 = gw * MNODE; n0 < n_nodes; n0 += nw * MNODE) {
        const int cnt = min(MNODE, n_nodes - n0);
        float x[MNODE];
#pragma unroll
        for (int m = 0; m < MNODE; m++)
            x[m] = (m < cnt) ? node[(size_t)(n0 + m) * 64 + lane] : 0.f;

        float acc[MNODE];
#pragma unroll
        for (int m = 0; m < MNODE; m++) acc[m] = bsc;
#pragma unroll
        for (int k = 0; k < 64; k++) {
            float wv = WsT[k * 64 + lane];
#pragma unroll
            for (int m = 0; m < MNODE; m++) acc[m] += rdlane(x[m], k) * wv;
        }
        float s1[MNODE];
#pragma unroll
        for (int m = 0; m < MNODE; m++) {
            float a = acc[m];
            s1[m] = a / (1.f + __expf(-a));
        }
        float a0[MNODE], a1[MNODE], a2[MNODE];
#pragma unroll
        for (int m = 0; m < MNODE; m++) { a0[m] = bp0; a1[m] = bp1; a2[m] = bp2; }
#pragma unroll
        for (int k = 0; k < 64; k++) {
            float w0 = WphiT[k * 192 + lane];
            float w1 = WphiT[k * 192 + 64 + lane];
            float w2 = WphiT[k * 192 + 128 + lane];
#pragma unroll
            for (int m = 0; m < MNODE; m++) {
                float sv = rdlane(s1[m], k);
                a0[m] += sv * w0;
                a1[m] += sv * w1;
                a2[m] += sv * w2;
            }
        }
#pragma unroll
        for (int m = 0; m < MNODE; m++) {
            if (m < cnt) {
                size_t nn = (size_t)(n0 + m);
                float q0 = eq[nn * 192 + lane];
                float q1 = eq[nn * 192 + 64 + lane];
                float q2 = eq[nn * 192 + 128 + lane];
                uint_t* p = (uint_t*)(sq + nn * 384 + lane * 6);   // 4B aligned
                p[0] = pack2bf(a0[m], a1[m]);                       // slots 0,1
                p[1] = (uint_t)f2bf(a2[m]) | ((uint_t)f2bf(q0) << 16); // slots 2,3
                p[2] = pack2bf(q1, q2);                             // slots 4,5
            }
        }
    }
}

// ---------------------------------------------------------------------------
// accum10 (round-11 verified, UNCHANGED): register-resident bf16 weights,
// rbf unpacked-f32 in LDS, 12B fused gather with depth-1 prefetch.
// ---------------------------------------------------------------------------
__global__ __launch_bounds__(256, 4)
void accum10_kernel(const ushort_t* __restrict__ sq,
                    const uint4* __restrict__ rec,
                    const uint_t* __restrict__ wpkp,
                    const float* __restrict__ bw,
                    float* __restrict__ ds, float* __restrict__ dv, int n_edges)
{
    __shared__ int    sh_dst[4 * 64];
    __shared__ int    sh_src[4 * 64];
    __shared__ float  sh_env[4 * 64];
    __shared__ float  sh_r[4 * 3 * 64];            // [w][comp][edge]
    __shared__ float4 sh_rbf[4 * 64 * 5];          // [w][edge][q] unpacked f32

    const int lane = threadIdx.x & 63;
    const int w = threadIdx.x >> 6;
    const int tile = blockIdx.x * 4 + w;
    const int base = tile * 64;
    const int nvalid = min(64, n_edges - base);
    const int woff = w * 64;

    // ---- all 60 weights for this lane: 30 packed u32, register-resident ----
    uint_t wp[30];
#pragma unroll
    for (int i = 0; i < 30; i++) wp[i] = wpkp[i * 64 + lane];

    // ---- Phase 1: lane = edge, unpack 64B record ----
    if (lane < nvalid) {
        size_t rp = (size_t)(base + lane) * 4;
        uint4 qa = rec[rp], qb = rec[rp + 1], qc = rec[rp + 2], qd = rec[rp + 3];
        sh_src[woff + lane] = (int)qa.x;
        sh_dst[woff + lane] = (int)qa.y;
        sh_env[woff + lane] = __uint_as_float(qa.z);
        sh_r[w * 192 + lane]       = __uint_as_float(qa.w);
        sh_r[w * 192 + 64 + lane]  = __uint_as_float(qb.x);
        sh_r[w * 192 + 128 + lane] = __uint_as_float(qb.y);
        float4* dstq = &sh_rbf[(woff + lane) * 5];
        dstq[0] = make_float4(bflo(qb.z), bfhi(qb.z), bflo(qb.w), bfhi(qb.w));
        dstq[1] = make_float4(bflo(qc.x), bfhi(qc.x), bflo(qc.y), bfhi(qc.y));
        dstq[2] = make_float4(bflo(qc.z), bfhi(qc.z), bflo(qc.w), bfhi(qc.w));
        dstq[3] = make_float4(bflo(qd.x), bfhi(qd.x), bflo(qd.y), bfhi(qd.y));
        dstq[4] = make_float4(bflo(qd.z), bfhi(qd.z), bflo(qd.w), bfhi(qd.w));
    }
    __syncthreads();

    if (nvalid <= 0) return;

    const float bw0 = bw[lane], bw1 = bw[64 + lane], bw2 = bw[128 + lane];

    float a0 = 0.f, a1 = 0.f, a2 = 0.f, a3 = 0.f;
    int cur = sh_dst[woff];

    // prefetch edge 0's gather
    U3 gcur = *(const U3*)(sq + (size_t)sh_src[woff] * 384 + lane * 6);

    // ---- Phase 2: lane = channel ----
    for (int j = 0; j < nvalid; j++) {
        int jn = (j + 1 < nvalid) ? j + 1 : j;
        U3 gnxt = *(const U3*)(sq + (size_t)sh_src[woff + jn] * 384 + lane * 6);

        float ev = sh_env[woff + j];
        float r0 = sh_r[w * 192 + j];
        float r1 = sh_r[w * 192 + 64 + j];
        float r2 = sh_r[w * 192 + 128 + j];

        float sv0 = bflo(gcur.a);
        float sv1 = bfhi(gcur.a);
        float sv2 = bflo(gcur.b);
        float v0  = bfhi(gcur.b);
        float v1  = bflo(gcur.c);
        float v2  = bfhi(gcur.c);

        float w0 = bw0, w1 = bw1, w2 = bw2;
#pragma unroll
        for (int q = 0; q < 5; q++) {
            float4 rb = sh_rbf[(woff + j) * 5 + q];
            uint_t wa0 = wp[2 * q],      wa1 = wp[2 * q + 1];       // c=0
            uint_t wb0 = wp[10 + 2 * q], wb1 = wp[11 + 2 * q];      // c=1
            uint_t wc0 = wp[20 + 2 * q], wc1 = wp[21 + 2 * q];      // c=2
            w0 += rb.x * bflo(wa0) + rb.y * bfhi(wa0) + rb.z * bflo(wa1) + rb.w * bfhi(wa1);
            w1 += rb.x * bflo(wb0) + rb.y * bfhi(wb0) + rb.z * bflo(wb1) + rb.w * bfhi(wb1);
            w2 += rb.x * bflo(wc0) + rb.y * bfhi(wc0) + rb.z * bflo(wc1) + rb.w * bfhi(wc1);
        }
        w0 *= ev; w1 *= ev; w2 *= ev;

        float sw1 = sv1 * w1;
        float sw2 = sv2 * w2;
        a0 += sv0 * w0;
        a1 += v0 * sw1 + r0 * sw2;
        a2 += v1 * sw1 + r1 * sw2;
        a3 += v2 * sw1 + r2 * sw2;

        int nd = (j + 1 < nvalid) ? sh_dst[woff + j + 1] : -2;
        if (nd != cur) {
            unsafeAtomicAdd(&ds[(size_t)cur * 64 + lane], a0);
            size_t db = (size_t)cur * 192 + lane;
            unsafeAtomicAdd(&dv[db], a1);
            unsafeAtomicAdd(&dv[db + 64], a2);
            unsafeAtomicAdd(&dv[db + 128], a3);
            a0 = a1 = a2 = a3 = 0.f;
            cur = nd;
        }
        gcur = gnxt;
    }
}

// ===========================================================================
// T3 fallback (round-1, proven): row-major f32 s + atomic scatter.
// ===========================================================================
__global__ __launch_bounds__(256, 2)
void node_mlp_kernel(const float* __restrict__ node,
                     const float* __restrict__ Ws,
                     const float* __restrict__ bs,
                     const float* __restrict__ Wphi,
                     const float* __restrict__ bphi,
                     float* __restrict__ s_out,
                     int n_nodes)
{
    __shared__ float WsT[64 * 65];
    __shared__ float WphiT[64 * 193];
    const int t = threadIdx.x;
    for (int i = t; i < 64 * 64; i += 256) {
        int c = i >> 6, k = i & 63;
        WsT[k * 65 + c] = Ws[i];
    }
    for (int i = t; i < 192 * 64; i += 256) {
        int j = i >> 6, k = i & 63;
        WphiT[k * 193 + j] = Wphi[i];
    }
    __syncthreads();

    const int lane = t & 63;
    const int wave = t >> 6;
    const int nwaves = (gridDim.x * blockDim.x) >> 6;
    const float bsc = bs[lane];
    const float bp0 = bphi[lane], bp1 = bphi[64 + lane], bp2 = bphi[128 + lane];

    for (int n = blockIdx.x * 4 + wave; n < n_nodes; n += nwaves) {
        float x = node[(size_t)n * 64 + lane];
        float acc = bsc;
#pragma unroll
        for (int k = 0; k < 64; k++) acc += __shfl(x, k) * WsT[k * 65 + lane];
        float s1 = acc / (1.0f + __expf(-acc));
        float a0 = bp0, a1 = bp1, a2 = bp2;
#pragma unroll
        for (int k = 0; k < 64; k++) {
            float sk = __shfl(s1, k);
            a0 += sk * WphiT[k * 193 + lane];
            a1 += sk * WphiT[k * 193 + 64 + lane];
            a2 += sk * WphiT[k * 193 + 128 + lane];
        }
        size_t ob = (size_t)n * 192;
        s_out[ob + lane] = a0;
        s_out[ob + 64 + lane] = a1;
        s_out[ob + 128 + lane] = a2;
    }
}

__global__ __launch_bounds__(256)
void edge_kernel(const float* __restrict__ s,
                 const float* __restrict__ eq,
                 const float* __restrict__ rbf,
                 const float* __restrict__ env,
                 const float* __restrict__ rij,
                 const int* __restrict__ eidx,
                 const int* __restrict__ idx_flag,
                 const float* __restrict__ Ww,
                 const float* __restrict__ bw,
                 float* __restrict__ ds,
                 float* __restrict__ dv,
                 int n_edges)
{
    const int lane = threadIdx.x & 63;
    const int wglob = (blockIdx.x * blockDim.x + threadIdx.x) >> 6;
    const int nw = (gridDim.x * blockDim.x) >> 6;

    float ww0[NRAD], ww1[NRAD], ww2[NRAD];
#pragma unroll
    for (int k = 0; k < NRAD; k++) {
        ww0[k] = Ww[lane * NRAD + k];
        ww1[k] = Ww[(64 + lane) * NRAD + k];
        ww2[k] = Ww[(128 + lane) * NRAD + k];
    }
    const float bw0 = bw[lane], bw1 = bw[64 + lane], bw2 = bw[128 + lane];
    const int fmt32 = idx_flag[0];

    for (int e = wglob; e < n_edges; e += nw) {
        int dst, src;
        if (fmt32) {
            dst = eidx[2 * e];
            src = eidx[2 * e + 1];
        } else {
            const long long* e64 = (const long long*)eidx;
            dst = (int)e64[2 * e];
            src = (int)e64[2 * e + 1];
        }
        float ev = env[e];
        float r0 = rij[3 * e], r1 = rij[3 * e + 1], r2 = rij[3 * e + 2];
        float rb[NRAD];
#pragma unroll
        for (int k = 0; k < NRAD; k++) rb[k] = rbf[(size_t)e * NRAD + k];
        float w0 = bw0, w1 = bw1, w2 = bw2;
#pragma unroll
        for (int k = 0; k < NRAD; k++) {
            w0 += rb[k] * ww0[k];
            w1 += rb[k] * ww1[k];
            w2 += rb[k] * ww2[k];
        }
        w0 *= ev; w1 *= ev; w2 *= ev;

        size_t sb = (size_t)src * 192;
        float sw0 = s[sb + lane] * w0;
        float sw1 = s[sb + 64 + lane] * w1;
        float sw2 = s[sb + 128 + lane] * w2;
        float v0 = eq[sb + lane];
        float v1 = eq[sb + 64 + lane];
        float v2 = eq[sb + 128 + lane];

        unsafeAtomicAdd(&ds[(size_t)dst * 64 + lane], sw0);
        size_t db = (size_t)dst * 192;
        unsafeAtomicAdd(&dv[db + lane],       v0 * sw1 + r0 * sw2);
        unsafeAtomicAdd(&dv[db + 64 + lane],  v1 * sw1 + r1 * sw2);
        unsafeAtomicAdd(&dv[db + 128 + lane], v2 * sw1 + r2 * sw2);
    }
}

extern "C" void kernel_launch(void* const* d_in, const int* in_sizes, int n_in,
                              void* d_out, int out_size, void* d_ws, size_t ws_size,
                              hipStream_t stream)
{
    const float* node = (const float*)d_in[0];
    const float* eq   = (const float*)d_in[1];
    const float* rbf  = (const float*)d_in[2];
    const float* env  = (const float*)d_in[3];
    const float* rij  = (const float*)d_in[4];
    const int*   eidx = (const int*)d_in[5];
    const float* Ws   = (const float*)d_in[6];
    const float* bs   = (const float*)d_in[7];
    const float* Wphi = (const float*)d_in[8];
    const float* bphi = (const float*)d_in[9];
    const float* Ww   = (const float*)d_in[10];
    const float* bw   = (const float*)d_in[11];

    const int n_nodes = in_sizes[0] / 64;
    const int n_edges = in_sizes[3];

    float* out = (float*)d_out;
    float* ds = out;
    float* dv = out + (size_t)n_nodes * 64;
    char* ws = (char*)d_ws;

    const int ch = (n_nodes + 255) / 256;
    const int nb = (n_nodes + ch - 1) / ch;

    // ---- Tier-1 layout: interleaved sq[node][64][6] bf16 + 64B records ----
    {
        size_t off = 0;
        auto alloc = [&](size_t bytes) { size_t o = off; off = (off + bytes + 255) & ~(size_t)255; return o; };
        size_t o_sq   = alloc((size_t)n_nodes * 384 * sizeof(ushort_t));  // 6 ch interleaved
        size_t o_cnt  = alloc(2 * (size_t)n_nodes * sizeof(int));         // counts + cur
        size_t o_rec  = alloc((size_t)n_edges * 64);
        size_t o_wpk  = alloc(1920 * sizeof(uint_t));
        size_t o_bsum = alloc(512 * sizeof(int));
        size_t o_flag = alloc(16);
        if (ws_size >= off) {
            ushort_t* sq = (ushort_t*)(ws + o_sq);
            int* counts = (int*)(ws + o_cnt);
            int* cur = counts + n_nodes;
            uint4* rec = (uint4*)(ws + o_rec);
            uint_t* wpkp = (uint_t*)(ws + o_wpk);
            int* bsum = (int*)(ws + o_bsum);
            int* bscan = bsum + 256;
            int* flag = (int*)(ws + o_flag);

            hipMemsetAsync(counts, 0, (size_t)n_nodes * sizeof(int), stream);
            hipMemsetAsync(d_out, 0, (size_t)out_size * sizeof(float), stream);
            detect_idx_kernel<<<1, 64, 0, stream>>>(eidx, flag);
            prep_wpkp_kernel<<<8, 256, 0, stream>>>(Ww, wpkp);
            hist_kernel<<<1024, 256, 0, stream>>>(eidx, flag, counts, n_edges);
            scan1_kernel<<<nb, 256, 0, stream>>>(counts, bsum, n_nodes, ch);
            scan2_kernel<<<1, 256, 0, stream>>>(bsum, bscan, nb);
            scan3_kernel<<<nb, 256, 0, stream>>>(counts, bscan, cur, n_nodes, ch);
            const int n_chunks = (n_edges + 255) / 256;
            scatter_rec2_kernel<<<n_chunks, 256, 0, stream>>>(eidx, flag, cur, env, rij, rbf,
                                                              rec, n_edges);
            node_mlp4<<<512, 256, 0, stream>>>(node, eq, Ws, bs, Wphi, bphi, sq, n_nodes);
            const int n_tiles = (n_edges + 63) / 64;
            accum10_kernel<<<(n_tiles + 3) / 4, 256, 0, stream>>>(
                sq, rec, wpkp, bw, ds, dv, n_edges);
            return;
        }
    }

    // ---- Tier-3: round-1 fallback (simple, fits any workspace >= s buffer) ----
    {
        float* s_ws = (float*)d_ws;
        int* idx_flag = (int*)(ws + (size_t)n_nodes * 192 * sizeof(float));
        hipMemsetAsync(d_out, 0, (size_t)out_size * sizeof(float), stream);
        detect_idx_kernel<<<1, 64, 0, stream>>>(eidx, idx_flag);
        node_mlp_kernel<<<1024, 256, 0, stream>>>(node, Ws, bs, Wphi, bphi, s_ws, n_nodes);
        edge_kernel<<<4096, 256, 0, stream>>>(s_ws, eq, rbf, env, rij, eidx, idx_flag,
                                              Ww, bw, ds, dv, n_edges);
    }
}

// Round 13
// 547.087 us; speedup vs baseline: 1.1005x; 1.1005x over previous
//
#include <hip/hip_runtime.h>

#define NRAD 20
#define MNODE 8

typedef unsigned short ushort_t;
typedef unsigned int uint_t;

struct U3 { uint_t a, b, c; };   // 12B interleaved gather payload

__device__ __forceinline__ float rdlane(float v, int l)
{
    return __uint_as_float(__builtin_amdgcn_readlane(__float_as_uint(v), l));
}

__device__ __forceinline__ ushort_t f2bf(float f)
{
    uint_t u = __float_as_uint(f);
    u += 0x7fff + ((u >> 16) & 1);   // round-to-nearest-even
    return (ushort_t)(u >> 16);
}

__device__ __forceinline__ uint_t pack2bf(float a, float b)
{
    return (uint_t)f2bf(a) | ((uint_t)f2bf(b) << 16);
}

__device__ __forceinline__ float bflo(uint_t w) { return __uint_as_float(w << 16); }
__device__ __forceinline__ float bfhi(uint_t w) { return __uint_as_float(w & 0xffff0000u); }
__device__ __forceinline__ float bf2f(ushort_t h) { return __uint_as_float(((uint_t)h) << 16); }

// ---------------------------------------------------------------------------
// Detect edge_index storage: int32 (flag=1) vs int64 (flag=0).
// ---------------------------------------------------------------------------
__global__ void detect_idx_kernel(const int* __restrict__ eidx, int* __restrict__ flag)
{
    int t = threadIdx.x;  // 64 threads, one wave
    unsigned long long m = __ballot(eidx[2 * t + 1] != 0);
    if (t == 0) flag[0] = (__popcll(m) > 8) ? 1 : 0;
}

// ---------------------------------------------------------------------------
// CSR build: histogram, 3-stage scan -> cur, then record-building scatter.
// ---------------------------------------------------------------------------
__global__ void hist_kernel(const int* __restrict__ eidx, const int* __restrict__ flag,
                            int* __restrict__ counts, int n_edges)
{
    int fmt32 = flag[0];
    int i0 = blockIdx.x * blockDim.x + threadIdx.x;
    int stride = gridDim.x * blockDim.x;
    if (fmt32) {
        for (int e = i0; e < n_edges; e += stride) atomicAdd(&counts[eidx[2 * e]], 1);
    } else {
        const long long* e64 = (const long long*)eidx;
        for (int e = i0; e < n_edges; e += stride) atomicAdd(&counts[(int)e64[2 * e]], 1);
    }
}

__global__ __launch_bounds__(256)
void scan1_kernel(const int* __restrict__ cnt, int* __restrict__ bsum, int n, int ch)
{
    __shared__ int red[4];
    int b = blockIdx.x, t = threadIdx.x;
    int end = min(n, (b + 1) * ch);
    int v = 0;
    for (int i = b * ch + t; i < end; i += 256) v += cnt[i];
#pragma unroll
    for (int d = 1; d < 64; d <<= 1) v += __shfl_xor(v, d, 64);
    if ((t & 63) == 0) red[t >> 6] = v;
    __syncthreads();
    if (t == 0) bsum[b] = red[0] + red[1] + red[2] + red[3];
}

__global__ __launch_bounds__(256)
void scan2_kernel(const int* __restrict__ bsum, int* __restrict__ bscan, int nb)
{
    __shared__ int wsum[4];
    int t = threadIdx.x, lane = t & 63, w = t >> 6;
    int v = (t < nb) ? bsum[t] : 0;
    int sc = v;
#pragma unroll
    for (int d = 1; d < 64; d <<= 1) {
        int u = __shfl_up(sc, (unsigned)d, 64);
        if (lane >= d) sc += u;
    }
    if (lane == 63) wsum[w] = sc;
    __syncthreads();
    int add = 0;
    for (int j = 0; j < w; j++) add += wsum[j];
    if (t < nb) bscan[t] = (sc + add) - v;
}

__global__ __launch_bounds__(256)
void scan3_kernel(const int* __restrict__ cnt, const int* __restrict__ bscan,
                  int* __restrict__ cur, int n, int ch)
{
    __shared__ int wsum[4];
    __shared__ int btot;
    int b = blockIdx.x, t = threadIdx.x, lane = t & 63, w = t >> 6;
    int end = min(n, (b + 1) * ch);
    int carry = bscan[b];
    for (int base = b * ch; base < end; base += 256) {
        int i = base + t;
        int v = (i < end) ? cnt[i] : 0;
        int sc = v;
#pragma unroll
        for (int d = 1; d < 64; d <<= 1) {
            int u = __shfl_up(sc, (unsigned)d, 64);
            if (lane >= d) sc += u;
        }
        if (lane == 63) wsum[w] = sc;
        __syncthreads();
        int add = 0;
        for (int j = 0; j < w; j++) add += wsum[j];
        if (t == 255) btot = sc + add;
        int excl = carry + (sc + add - v);
        if (i < end) cur[i] = excl;
        __syncthreads();
        carry += btot;
    }
}

// ---------------------------------------------------------------------------
// scatter_rec2: LDS-staged record build (round-12, correctness-proven).
// Coalesced rbf/rij/env reads; padded stride-21 rbf readback (conflict-free).
// Record layout: {src,dst,env,r0} {r1,r2,w0,w1} {w2..w5} {w6..w9}.
// ---------------------------------------------------------------------------
__global__ __launch_bounds__(256)
void scatter_rec2_kernel(const int* __restrict__ eidx, const int* __restrict__ flag,
                         int* __restrict__ cur,
                         const float* __restrict__ env, const float* __restrict__ rij,
                         const float* __restrict__ rbf,
                         uint4* __restrict__ rec, int n_edges)
{
    __shared__ float s_rbf[256 * 21];    // padded
    __shared__ float s_rij[256 * 3];
    __shared__ float s_env[256];

    const int t = threadIdx.x;
    const int chunk = blockIdx.x * 256;
    const int nval = min(256, n_edges - chunk);
    if (nval <= 0) return;

    for (int i = t; i < nval * 20; i += 256) {
        int e2 = i / 20, k = i - e2 * 20;
        s_rbf[e2 * 21 + k] = rbf[(size_t)chunk * 20 + i];
    }
    for (int i = t; i < nval * 3; i += 256) s_rij[i] = rij[(size_t)chunk * 3 + i];
    for (int i = t; i < nval; i += 256)     s_env[i] = env[chunk + i];
    __syncthreads();

    if (t < nval) {
        const int e = chunk + t;
        int dst, src;
        if (flag[0]) { dst = eidx[2 * e]; src = eidx[2 * e + 1]; }
        else {
            const long long* e64 = (const long long*)eidx;
            dst = (int)e64[2 * e]; src = (int)e64[2 * e + 1];
        }
        int pos = atomicAdd(&cur[dst], 1);
        float ev = s_env[t];
        float r0 = s_rij[3 * t], r1 = s_rij[3 * t + 1], r2 = s_rij[3 * t + 2];
        const float* rb = &s_rbf[t * 21];
        uint4 qa, qb, qc, qd;
        qa.x = (uint_t)src; qa.y = (uint_t)dst;
        qa.z = __float_as_uint(ev); qa.w = __float_as_uint(r0);
        qb.x = __float_as_uint(r1); qb.y = __float_as_uint(r2);
        qb.z = pack2bf(rb[0], rb[1]);   qb.w = pack2bf(rb[2], rb[3]);
        qc.x = pack2bf(rb[4], rb[5]);   qc.y = pack2bf(rb[6], rb[7]);
        qc.z = pack2bf(rb[8], rb[9]);   qc.w = pack2bf(rb[10], rb[11]);
        qd.x = pack2bf(rb[12], rb[13]); qd.y = pack2bf(rb[14], rb[15]);
        qd.z = pack2bf(rb[16], rb[17]); qd.w = pack2bf(rb[18], rb[19]);
        size_t rp = (size_t)pos * 4;
        rec[rp] = qa; rec[rp + 1] = qb; rec[rp + 2] = qc; rec[rp + 3] = qd;
    }
}

// ---------------------------------------------------------------------------
// eq -> interleaved slots 3..5 of sq[node][lane][6] (ushort).  (round-11)
// ---------------------------------------------------------------------------
__global__ void eq_cast_i_kernel(const float* __restrict__ eq,
                                 ushort_t* __restrict__ sq, int n_nodes)
{
    int i0 = blockIdx.x * blockDim.x + threadIdx.x;
    int stride = gridDim.x * blockDim.x;
    int total = n_nodes * 192;
    for (int i = i0; i < total; i += stride) {
        int n = i / 192;
        int r = i - n * 192;
        int c = r >> 6, ch = r & 63;
        sq[(size_t)n * 384 + ch * 6 + 3 + c] = f2bf(eq[i]);
    }
}

// ---------------------------------------------------------------------------
// Pack Ww into per-lane bf16 pair table (round-11 proven).
// ---------------------------------------------------------------------------
__global__ void prep_wpkp_kernel(const float* __restrict__ Ww, uint_t* __restrict__ wpkp)
{
    int idx = blockIdx.x * 256 + threadIdx.x;
    if (idx >= 1920) return;
    int lane = idx & 63;
    int r = idx >> 6;          // 0..29 = c*10+p
    int p = r % 10;
    int c = r / 10;
    int n = c * 64 + lane;
    wpkp[idx] = pack2bf(Ww[n * 20 + 2 * p], Ww[n * 20 + 2 * p + 1]);
}

// ---------------------------------------------------------------------------
// node_mlp3j: round-11 node_mlp3i structure + LDS diet.
//   r12 PMC showed the MLP kernel at 64KB LDS -> 1 block/CU (Occupancy 10%)
//   + 8.1M bank conflicts from the stride-192 staging writes (192 % 32 == 0
//   -> 64-way).  Fix: WphiT stored bf16 (ushort, padded stride 193, 24.7KB),
//   WsT padded stride 65 (16.6KB) -> LDS ~41.4KB -> 3 blocks/CU; both
//   staging patterns now conflict-free ((k+j)%32 spread / 2B-stride 2-way).
//   Numerics: only Wphi is bf16-rounded (|Wphi|<=0.125); a* error ~4e-3
//   pre-round vs 0.0753 threshold.  Epilogue = round-11 (slots 0..2 of sq).
// ---------------------------------------------------------------------------
__global__ __launch_bounds__(256)
void node_mlp3j(const float* __restrict__ node,
                const float* __restrict__ Ws, const float* __restrict__ bs,
                const float* __restrict__ Wphi, const float* __restrict__ bphi,
                ushort_t* __restrict__ sq, int n_nodes)
{
    __shared__ float    WsT[64 * 65];     // [k][j] = Ws[j][k], padded
    __shared__ ushort_t WphiH[64 * 193];  // [k][j] = bf16(Wphi[j][k]), padded
    const int t = threadIdx.x;
    for (int i = t; i < 64 * 64; i += 256) {
        int j = i >> 6, k = i & 63;
        WsT[k * 65 + j] = Ws[i];
    }
    for (int i = t; i < 192 * 64; i += 256) {
        int j = i >> 6, k = i & 63;
        WphiH[k * 193 + j] = f2bf(Wphi[i]);
    }
    __syncthreads();

    const int lane = t & 63;
    const int wave = t >> 6;
    const int gw = blockIdx.x * 4 + wave;
    const int nw = gridDim.x * 4;
    const float bsc = bs[lane];
    const float bp0 = bphi[lane], bp1 = bphi[64 + lane], bp2 = bphi[128 + lane];

    for (int n0 = gw * MNODE; n0 < n_nodes; n0 += nw * MNODE) {
        const int cnt = min(MNODE, n_nodes - n0);
        float x[MNODE];
#pragma unroll
        for (int m = 0; m < MNODE; m++)
            x[m] = (m < cnt) ? node[(size_t)(n0 + m) * 64 + lane] : 0.f;

        float acc[MNODE];
#pragma unroll
        for (int m = 0; m < MNODE; m++) acc[m] = bsc;
#pragma unroll
        for (int k = 0; k < 64; k++) {
            float wv = WsT[k * 65 + lane];
#pragma unroll
            for (int m = 0; m < MNODE; m++) acc[m] += rdlane(x[m], k) * wv;
        }
        float s1[MNODE];
#pragma unroll
        for (int m = 0; m < MNODE; m++) {
            float a = acc[m];
            s1[m] = a / (1.f + __expf(-a));
        }
        float a0[MNODE], a1[MNODE], a2[MNODE];
#pragma unroll
        for (int m = 0; m < MNODE; m++) { a0[m] = bp0; a1[m] = bp1; a2[m] = bp2; }
#pragma unroll
        for (int k = 0; k < 64; k++) {
            float w0 = bf2f(WphiH[k * 193 + lane]);
            float w1 = bf2f(WphiH[k * 193 + 64 + lane]);
            float w2 = bf2f(WphiH[k * 193 + 128 + lane]);
#pragma unroll
            for (int m = 0; m < MNODE; m++) {
                float sv = rdlane(s1[m], k);
                a0[m] += sv * w0;
                a1[m] += sv * w1;
                a2[m] += sv * w2;
            }
        }
#pragma unroll
        for (int m = 0; m < MNODE; m++) {
            if (m < cnt) {
                size_t ob = (size_t)(n0 + m) * 384 + lane * 6;
                *(uint_t*)(sq + ob) = pack2bf(a0[m], a1[m]);   // slots 0,1 (4B-aligned)
                sq[ob + 2] = f2bf(a2[m]);                       // slot 2
            }
        }
    }
}

// ---------------------------------------------------------------------------
// accum10 (round-11 verified, UNCHANGED): register-resident bf16 weights,
// rbf unpacked-f32 in LDS, 12B fused gather with depth-1 prefetch.
// ---------------------------------------------------------------------------
__global__ __launch_bounds__(256, 4)
void accum10_kernel(const ushort_t* __restrict__ sq,
                    const uint4* __restrict__ rec,
                    const uint_t* __restrict__ wpkp,
                    const float* __restrict__ bw,
                    float* __restrict__ ds, float* __restrict__ dv, int n_edges)
{
    __shared__ int    sh_dst[4 * 64];
    __shared__ int    sh_src[4 * 64];
    __shared__ float  sh_env[4 * 64];
    __shared__ float  sh_r[4 * 3 * 64];            // [w][comp][edge]
    __shared__ float4 sh_rbf[4 * 64 * 5];          // [w][edge][q] unpacked f32

    const int lane = threadIdx.x & 63;
    const int w = threadIdx.x >> 6;
    const int tile = blockIdx.x * 4 + w;
    const int base = tile * 64;
    const int nvalid = min(64, n_edges - base);
    const int woff = w * 64;

    // ---- all 60 weights for this lane: 30 packed u32, register-resident ----
    uint_t wp[30];
#pragma unroll
    for (int i = 0; i < 30; i++) wp[i] = wpkp[i * 64 + lane];

    // ---- Phase 1: lane = edge, unpack 64B record ----
    if (lane < nvalid) {
        size_t rp = (size_t)(base + lane) * 4;
        uint4 qa = rec[rp], qb = rec[rp + 1], qc = rec[rp + 2], qd = rec[rp + 3];
        sh_src[woff + lane] = (int)qa.x;
        sh_dst[woff + lane] = (int)qa.y;
        sh_env[woff + lane] = __uint_as_float(qa.z);
        sh_r[w * 192 + lane]       = __uint_as_float(qa.w);
        sh_r[w * 192 + 64 + lane]  = __uint_as_float(qb.x);
        sh_r[w * 192 + 128 + lane] = __uint_as_float(qb.y);
        float4* dstq = &sh_rbf[(woff + lane) * 5];
        dstq[0] = make_float4(bflo(qb.z), bfhi(qb.z), bflo(qb.w), bfhi(qb.w));
        dstq[1] = make_float4(bflo(qc.x), bfhi(qc.x), bflo(qc.y), bfhi(qc.y));
        dstq[2] = make_float4(bflo(qc.z), bfhi(qc.z), bflo(qc.w), bfhi(qc.w));
        dstq[3] = make_float4(bflo(qd.x), bfhi(qd.x), bflo(qd.y), bfhi(qd.y));
        dstq[4] = make_float4(bflo(qd.z), bfhi(qd.z), bflo(qd.w), bfhi(qd.w));
    }
    __syncthreads();

    if (nvalid <= 0) return;

    const float bw0 = bw[lane], bw1 = bw[64 + lane], bw2 = bw[128 + lane];

    float a0 = 0.f, a1 = 0.f, a2 = 0.f, a3 = 0.f;
    int cur = sh_dst[woff];

    // prefetch edge 0's gather
    U3 gcur = *(const U3*)(sq + (size_t)sh_src[woff] * 384 + lane * 6);

    // ---- Phase 2: lane = channel ----
    for (int j = 0; j < nvalid; j++) {
        int jn = (j + 1 < nvalid) ? j + 1 : j;
        U3 gnxt = *(const U3*)(sq + (size_t)sh_src[woff + jn] * 384 + lane * 6);

        float ev = sh_env[woff + j];
        float r0 = sh_r[w * 192 + j];
        float r1 = sh_r[w * 192 + 64 + j];
        float r2 = sh_r[w * 192 + 128 + j];

        float sv0 = bflo(gcur.a);
        float sv1 = bfhi(gcur.a);
        float sv2 = bflo(gcur.b);
        float v0  = bfhi(gcur.b);
        float v1  = bflo(gcur.c);
        float v2  = bfhi(gcur.c);

        float w0 = bw0, w1 = bw1, w2 = bw2;
#pragma unroll
        for (int q = 0; q < 5; q++) {
            float4 rb = sh_rbf[(woff + j) * 5 + q];
            uint_t wa0 = wp[2 * q],      wa1 = wp[2 * q + 1];       // c=0
            uint_t wb0 = wp[10 + 2 * q], wb1 = wp[11 + 2 * q];      // c=1
            uint_t wc0 = wp[20 + 2 * q], wc1 = wp[21 + 2 * q];      // c=2
            w0 += rb.x * bflo(wa0) + rb.y * bfhi(wa0) + rb.z * bflo(wa1) + rb.w * bfhi(wa1);
            w1 += rb.x * bflo(wb0) + rb.y * bfhi(wb0) + rb.z * bflo(wb1) + rb.w * bfhi(wb1);
            w2 += rb.x * bflo(wc0) + rb.y * bfhi(wc0) + rb.z * bflo(wc1) + rb.w * bfhi(wc1);
        }
        w0 *= ev; w1 *= ev; w2 *= ev;

        float sw1 = sv1 * w1;
        float sw2 = sv2 * w2;
        a0 += sv0 * w0;
        a1 += v0 * sw1 + r0 * sw2;
        a2 += v1 * sw1 + r1 * sw2;
        a3 += v2 * sw1 + r2 * sw2;

        int nd = (j + 1 < nvalid) ? sh_dst[woff + j + 1] : -2;
        if (nd != cur) {
            unsafeAtomicAdd(&ds[(size_t)cur * 64 + lane], a0);
            size_t db = (size_t)cur * 192 + lane;
            unsafeAtomicAdd(&dv[db], a1);
            unsafeAtomicAdd(&dv[db + 64], a2);
            unsafeAtomicAdd(&dv[db + 128], a3);
            a0 = a1 = a2 = a3 = 0.f;
            cur = nd;
        }
        gcur = gnxt;
    }
}

// ===========================================================================
// T3 fallback (round-1, proven): row-major f32 s + atomic scatter.
// ===========================================================================
__global__ __launch_bounds__(256, 2)
void node_mlp_kernel(const float* __restrict__ node,
                     const float* __restrict__ Ws,
                     const float* __restrict__ bs,
                     const float* __restrict__ Wphi,
                     const float* __restrict__ bphi,
                     float* __restrict__ s_out,
                     int n_nodes)
{
    __shared__ float WsT[64 * 65];
    __shared__ float WphiT[64 * 193];
    const int t = threadIdx.x;
    for (int i = t; i < 64 * 64; i += 256) {
        int c = i >> 6, k = i & 63;
        WsT[k * 65 + c] = Ws[i];
    }
    for (int i = t; i < 192 * 64; i += 256) {
        int j = i >> 6, k = i & 63;
        WphiT[k * 193 + j] = Wphi[i];
    }
    __syncthreads();

    const int lane = t & 63;
    const int wave = t >> 6;
    const int nwaves = (gridDim.x * blockDim.x) >> 6;
    const float bsc = bs[lane];
    const float bp0 = bphi[lane], bp1 = bphi[64 + lane], bp2 = bphi[128 + lane];

    for (int n = blockIdx.x * 4 + wave; n < n_nodes; n += nwaves) {
        float x = node[(size_t)n * 64 + lane];
        float acc = bsc;
#pragma unroll
        for (int k = 0; k < 64; k++) acc += __shfl(x, k) * WsT[k * 65 + lane];
        float s1 = acc / (1.0f + __expf(-acc));
        float a0 = bp0, a1 = bp1, a2 = bp2;
#pragma unroll
        for (int k = 0; k < 64; k++) {
            float sk = __shfl(s1, k);
            a0 += sk * WphiT[k * 193 + lane];
            a1 += sk * WphiT[k * 193 + 64 + lane];
            a2 += sk * WphiT[k * 193 + 128 + lane];
        }
        size_t ob = (size_t)n * 192;
        s_out[ob + lane] = a0;
        s_out[ob + 64 + lane] = a1;
        s_out[ob + 128 + lane] = a2;
    }
}

__global__ __launch_bounds__(256)
void edge_kernel(const float* __restrict__ s,
                 const float* __restrict__ eq,
                 const float* __restrict__ rbf,
                 const float* __restrict__ env,
                 const float* __restrict__ rij,
                 const int* __restrict__ eidx,
                 const int* __restrict__ idx_flag,
                 const float* __restrict__ Ww,
                 const float* __restrict__ bw,
                 float* __restrict__ ds,
                 float* __restrict__ dv,
                 int n_edges)
{
    const int lane = threadIdx.x & 63;
    const int wglob = (blockIdx.x * blockDim.x + threadIdx.x) >> 6;
    const int nw = (gridDim.x * blockDim.x) >> 6;

    float ww0[NRAD], ww1[NRAD], ww2[NRAD];
#pragma unroll
    for (int k = 0; k < NRAD; k++) {
        ww0[k] = Ww[lane * NRAD + k];
        ww1[k] = Ww[(64 + lane) * NRAD + k];
        ww2[k] = Ww[(128 + lane) * NRAD + k];
    }
    const float bw0 = bw[lane], bw1 = bw[64 + lane], bw2 = bw[128 + lane];
    const int fmt32 = idx_flag[0];

    for (int e = wglob; e < n_edges; e += nw) {
        int dst, src;
        if (fmt32) {
            dst = eidx[2 * e];
            src = eidx[2 * e + 1];
        } else {
            const long long* e64 = (const long long*)eidx;
            dst = (int)e64[2 * e];
            src = (int)e64[2 * e + 1];
        }
        float ev = env[e];
        float r0 = rij[3 * e], r1 = rij[3 * e + 1], r2 = rij[3 * e + 2];
        float rb[NRAD];
#pragma unroll
        for (int k = 0; k < NRAD; k++) rb[k] = rbf[(size_t)e * NRAD + k];
        float w0 = bw0, w1 = bw1, w2 = bw2;
#pragma unroll
        for (int k = 0; k < NRAD; k++) {
            w0 += rb[k] * ww0[k];
            w1 += rb[k] * ww1[k];
            w2 += rb[k] * ww2[k];
        }
        w0 *= ev; w1 *= ev; w2 *= ev;

        size_t sb = (size_t)src * 192;
        float sw0 = s[sb + lane] * w0;
        float sw1 = s[sb + 64 + lane] * w1;
        float sw2 = s[sb + 128 + lane] * w2;
        float v0 = eq[sb + lane];
        float v1 = eq[sb + 64 + lane];
        float v2 = eq[sb + 128 + lane];

        unsafeAtomicAdd(&ds[(size_t)dst * 64 + lane], sw0);
        size_t db = (size_t)dst * 192;
        unsafeAtomicAdd(&dv[db + lane],       v0 * sw1 + r0 * sw2);
        unsafeAtomicAdd(&dv[db + 64 + lane],  v1 * sw1 + r1 * sw2);
        unsafeAtomicAdd(&dv[db + 128 + lane], v2 * sw1 + r2 * sw2);
    }
}

extern "C" void kernel_launch(void* const* d_in, const int* in_sizes, int n_in,
                              void* d_out, int out_size, void* d_ws, size_t ws_size,
                              hipStream_t stream)
{
    const float* node = (const float*)d_in[0];
    const float* eq   = (const float*)d_in[1];
    const float* rbf  = (const float*)d_in[2];
    const float* env  = (const float*)d_in[3];
    const float* rij  = (const float*)d_in[4];
    const int*   eidx = (const int*)d_in[5];
    const float* Ws   = (const float*)d_in[6];
    const float* bs   = (const float*)d_in[7];
    const float* Wphi = (const float*)d_in[8];
    const float* bphi = (const float*)d_in[9];
    const float* Ww   = (const float*)d_in[10];
    const float* bw   = (const float*)d_in[11];

    const int n_nodes = in_sizes[0] / 64;
    const int n_edges = in_sizes[3];

    float* out = (float*)d_out;
    float* ds = out;
    float* dv = out + (size_t)n_nodes * 64;
    char* ws = (char*)d_ws;

    const int ch = (n_nodes + 255) / 256;
    const int nb = (n_nodes + ch - 1) / ch;

    // ---- Tier-1 layout: interleaved sq[node][64][6] bf16 + 64B records ----
    {
        size_t off = 0;
        auto alloc = [&](size_t bytes) { size_t o = off; off = (off + bytes + 255) & ~(size_t)255; return o; };
        size_t o_sq   = alloc((size_t)n_nodes * 384 * sizeof(ushort_t));  // 6 ch interleaved
        size_t o_cnt  = alloc(2 * (size_t)n_nodes * sizeof(int));         // counts + cur
        size_t o_rec  = alloc((size_t)n_edges * 64);
        size_t o_wpk  = alloc(1920 * sizeof(uint_t));
        size_t o_bsum = alloc(512 * sizeof(int));
        size_t o_flag = alloc(16);
        if (ws_size >= off) {
            ushort_t* sq = (ushort_t*)(ws + o_sq);
            int* counts = (int*)(ws + o_cnt);
            int* cur = counts + n_nodes;
            uint4* rec = (uint4*)(ws + o_rec);
            uint_t* wpkp = (uint_t*)(ws + o_wpk);
            int* bsum = (int*)(ws + o_bsum);
            int* bscan = bsum + 256;
            int* flag = (int*)(ws + o_flag);

            hipMemsetAsync(counts, 0, (size_t)n_nodes * sizeof(int), stream);
            hipMemsetAsync(d_out, 0, (size_t)out_size * sizeof(float), stream);
            detect_idx_kernel<<<1, 64, 0, stream>>>(eidx, flag);
            prep_wpkp_kernel<<<8, 256, 0, stream>>>(Ww, wpkp);
            hist_kernel<<<1024, 256, 0, stream>>>(eidx, flag, counts, n_edges);
            scan1_kernel<<<nb, 256, 0, stream>>>(counts, bsum, n_nodes, ch);
            scan2_kernel<<<1, 256, 0, stream>>>(bsum, bscan, nb);
            scan3_kernel<<<nb, 256, 0, stream>>>(counts, bscan, cur, n_nodes, ch);
            const int n_chunks = (n_edges + 255) / 256;
            scatter_rec2_kernel<<<n_chunks, 256, 0, stream>>>(eidx, flag, cur, env, rij, rbf,
                                                              rec, n_edges);
            eq_cast_i_kernel<<<1024, 256, 0, stream>>>(eq, sq, n_nodes);
            node_mlp3j<<<512, 256, 0, stream>>>(node, Ws, bs, Wphi, bphi, sq, n_nodes);
            const int n_tiles = (n_edges + 63) / 64;
            accum10_kernel<<<(n_tiles + 3) / 4, 256, 0, stream>>>(
                sq, rec, wpkp, bw, ds, dv, n_edges);
            return;
        }
    }

    // ---- Tier-3: round-1 fallback (simple, fits any workspace >= s buffer) ----
    {
        float* s_ws = (float*)d_ws;
        int* idx_flag = (int*)(ws + (size_t)n_nodes * 192 * sizeof(float));
        hipMemsetAsync(d_out, 0, (size_t)out_size * sizeof(float), stream);
        detect_idx_kernel<<<1, 64, 0, stream>>>(eidx, idx_flag);
        node_mlp_kernel<<<1024, 256, 0, stream>>>(node, Ws, bs, Wphi, bphi, s_ws, n_nodes);
        edge_kernel<<<4096, 256, 0, stream>>>(s_ws, eq, rbf, env, rij, eidx, idx_flag,
                                              Ww, bw, ds, dv, n_edges);
    }
}

// Round 14
// 532.339 us; speedup vs baseline: 1.1310x; 1.0277x over previous
//
#include <hip/hip_runtime.h>

#define NRAD 20
#define MNODE 8

typedef unsigned short ushort_t;
typedef unsigned int uint_t;

struct U3 { uint_t a, b, c; };   // 12B interleaved gather payload

__device__ __forceinline__ float rdlane(float v, int l)
{
    return __uint_as_float(__builtin_amdgcn_readlane(__float_as_uint(v), l));
}

__device__ __forceinline__ ushort_t f2bf(float f)
{
    uint_t u = __float_as_uint(f);
    u += 0x7fff + ((u >> 16) & 1);   // round-to-nearest-even
    return (ushort_t)(u >> 16);
}

__device__ __forceinline__ uint_t pack2bf(float a, float b)
{
    return (uint_t)f2bf(a) | ((uint_t)f2bf(b) << 16);
}

__device__ __forceinline__ float bflo(uint_t w) { return __uint_as_float(w << 16); }
__device__ __forceinline__ float bfhi(uint_t w) { return __uint_as_float(w & 0xffff0000u); }
__device__ __forceinline__ float bf2f(ushort_t h) { return __uint_as_float(((uint_t)h) << 16); }

// ---------------------------------------------------------------------------
// Detect edge_index storage: int32 (flag=1) vs int64 (flag=0).
// ---------------------------------------------------------------------------
__global__ void detect_idx_kernel(const int* __restrict__ eidx, int* __restrict__ flag)
{
    int t = threadIdx.x;  // 64 threads, one wave
    unsigned long long m = __ballot(eidx[2 * t + 1] != 0);
    if (t == 0) flag[0] = (__popcll(m) > 8) ? 1 : 0;
}

// ---------------------------------------------------------------------------
// CSR build: histogram, 3-stage scan -> cur, then record-building scatter.
// ---------------------------------------------------------------------------
__global__ void hist_kernel(const int* __restrict__ eidx, const int* __restrict__ flag,
                            int* __restrict__ counts, int n_edges)
{
    int fmt32 = flag[0];
    int i0 = blockIdx.x * blockDim.x + threadIdx.x;
    int stride = gridDim.x * blockDim.x;
    if (fmt32) {
        for (int e = i0; e < n_edges; e += stride) atomicAdd(&counts[eidx[2 * e]], 1);
    } else {
        const long long* e64 = (const long long*)eidx;
        for (int e = i0; e < n_edges; e += stride) atomicAdd(&counts[(int)e64[2 * e]], 1);
    }
}

__global__ __launch_bounds__(256)
void scan1_kernel(const int* __restrict__ cnt, int* __restrict__ bsum, int n, int ch)
{
    __shared__ int red[4];
    int b = blockIdx.x, t = threadIdx.x;
    int end = min(n, (b + 1) * ch);
    int v = 0;
    for (int i = b * ch + t; i < end; i += 256) v += cnt[i];
#pragma unroll
    for (int d = 1; d < 64; d <<= 1) v += __shfl_xor(v, d, 64);
    if ((t & 63) == 0) red[t >> 6] = v;
    __syncthreads();
    if (t == 0) bsum[b] = red[0] + red[1] + red[2] + red[3];
}

__global__ __launch_bounds__(256)
void scan2_kernel(const int* __restrict__ bsum, int* __restrict__ bscan, int nb)
{
    __shared__ int wsum[4];
    int t = threadIdx.x, lane = t & 63, w = t >> 6;
    int v = (t < nb) ? bsum[t] : 0;
    int sc = v;
#pragma unroll
    for (int d = 1; d < 64; d <<= 1) {
        int u = __shfl_up(sc, (unsigned)d, 64);
        if (lane >= d) sc += u;
    }
    if (lane == 63) wsum[w] = sc;
    __syncthreads();
    int add = 0;
    for (int j = 0; j < w; j++) add += wsum[j];
    if (t < nb) bscan[t] = (sc + add) - v;
}

__global__ __launch_bounds__(256)
void scan3_kernel(const int* __restrict__ cnt, const int* __restrict__ bscan,
                  int* __restrict__ cur, int n, int ch)
{
    __shared__ int wsum[4];
    __shared__ int btot;
    int b = blockIdx.x, t = threadIdx.x, lane = t & 63, w = t >> 6;
    int end = min(n, (b + 1) * ch);
    int carry = bscan[b];
    for (int base = b * ch; base < end; base += 256) {
        int i = base + t;
        int v = (i < end) ? cnt[i] : 0;
        int sc = v;
#pragma unroll
        for (int d = 1; d < 64; d <<= 1) {
            int u = __shfl_up(sc, (unsigned)d, 64);
            if (lane >= d) sc += u;
        }
        if (lane == 63) wsum[w] = sc;
        __syncthreads();
        int add = 0;
        for (int j = 0; j < w; j++) add += wsum[j];
        if (t == 255) btot = sc + add;
        int excl = carry + (sc + add - v);
        if (i < end) cur[i] = excl;
        __syncthreads();
        carry += btot;
    }
}

// ---------------------------------------------------------------------------
// scatter_rec (round-11 proven): build 64-byte sorted edge records.
// NOTE (r13 post-mortem): the five stride-80 float4 loads of a wave jointly
// cover a CONTIGUOUS span -> no cache overfetch; the LDS-staged variant
// (scatter_rec2) bought nothing and added staging cost.  Keep this one.
// rec layout (4x uint4): {src,dst,env,r0} {r1,r2,w0,w1} {w2..w5} {w6..w9}.
// ---------------------------------------------------------------------------
__global__ void scatter_rec_kernel(const int* __restrict__ eidx, const int* __restrict__ flag,
                                   int* __restrict__ cur,
                                   const float* __restrict__ env, const float* __restrict__ rij,
                                   const float* __restrict__ rbf,
                                   uint4* __restrict__ rec, int n_edges)
{
    int fmt32 = flag[0];
    int i0 = blockIdx.x * blockDim.x + threadIdx.x;
    int stride = gridDim.x * blockDim.x;
    const long long* e64 = (const long long*)eidx;
    const float4* rbf4 = (const float4*)rbf;
    for (int e = i0; e < n_edges; e += stride) {
        int dst, src;
        if (fmt32) { dst = eidx[2 * e]; src = eidx[2 * e + 1]; }
        else       { dst = (int)e64[2 * e]; src = (int)e64[2 * e + 1]; }
        int pos = atomicAdd(&cur[dst], 1);
        float ev = env[e];
        float r0 = rij[3 * e], r1 = rij[3 * e + 1], r2 = rij[3 * e + 2];
        float4 b0 = rbf4[(size_t)e * 5 + 0];
        float4 b1 = rbf4[(size_t)e * 5 + 1];
        float4 b2 = rbf4[(size_t)e * 5 + 2];
        float4 b3 = rbf4[(size_t)e * 5 + 3];
        float4 b4 = rbf4[(size_t)e * 5 + 4];
        uint4 qa, qb, qc, qd;
        qa.x = (uint_t)src; qa.y = (uint_t)dst;
        qa.z = __float_as_uint(ev); qa.w = __float_as_uint(r0);
        qb.x = __float_as_uint(r1); qb.y = __float_as_uint(r2);
        qb.z = pack2bf(b0.x, b0.y); qb.w = pack2bf(b0.z, b0.w);
        qc.x = pack2bf(b1.x, b1.y); qc.y = pack2bf(b1.z, b1.w);
        qc.z = pack2bf(b2.x, b2.y); qc.w = pack2bf(b2.z, b2.w);
        qd.x = pack2bf(b3.x, b3.y); qd.y = pack2bf(b3.z, b3.w);
        qd.z = pack2bf(b4.x, b4.y); qd.w = pack2bf(b4.z, b4.w);
        size_t rp = (size_t)pos * 4;
        rec[rp] = qa; rec[rp + 1] = qb; rec[rp + 2] = qc; rec[rp + 3] = qd;
    }
}

// ---------------------------------------------------------------------------
// eq_cast_i2: (node,ch)-major; 3 coalesced f32 reads; slots 3..5 written as
// one u16 + one u32 (2 stores instead of 3).  Rounding identical to eq_cast_i.
// ---------------------------------------------------------------------------
__global__ void eq_cast_i2_kernel(const float* __restrict__ eq,
                                  ushort_t* __restrict__ sq, int n_nodes)
{
    int i0 = blockIdx.x * blockDim.x + threadIdx.x;
    int stride = gridDim.x * blockDim.x;
    int total = n_nodes * 64;
    for (int i = i0; i < total; i += stride) {
        int n = i >> 6, ch = i & 63;
        size_t eb = (size_t)n * 192 + ch;
        float q0 = eq[eb];
        float q1 = eq[eb + 64];
        float q2 = eq[eb + 128];
        size_t ob = (size_t)n * 384 + ch * 6;
        sq[ob + 3] = f2bf(q0);                        // slot 3 (u16)
        *(uint_t*)(sq + ob + 4) = pack2bf(q1, q2);    // slots 4,5 (u32, 4B-aligned)
    }
}

// ---------------------------------------------------------------------------
// Pack Ww into per-lane bf16 pair table (round-11 proven).
// ---------------------------------------------------------------------------
__global__ void prep_wpkp_kernel(const float* __restrict__ Ww, uint_t* __restrict__ wpkp)
{
    int idx = blockIdx.x * 256 + threadIdx.x;
    if (idx >= 1920) return;
    int lane = idx & 63;
    int r = idx >> 6;          // 0..29 = c*10+p
    int p = r % 10;
    int c = r / 10;
    int n = c * 64 + lane;
    wpkp[idx] = pack2bf(Ww[n * 20 + 2 * p], Ww[n * 20 + 2 * p + 1]);
}

// ---------------------------------------------------------------------------
// node_mlp3j (round-13 proven): LDS diet (41.4KB -> 3 blocks/CU) +
// conflict-free staging.  WphiT bf16 padded 193; WsT f32 padded 65.
// ---------------------------------------------------------------------------
__global__ __launch_bounds__(256)
void node_mlp3j(const float* __restrict__ node,
                const float* __restrict__ Ws, const float* __restrict__ bs,
                const float* __restrict__ Wphi, const float* __restrict__ bphi,
                ushort_t* __restrict__ sq, int n_nodes)
{
    __shared__ float    WsT[64 * 65];     // [k][j] = Ws[j][k], padded
    __shared__ ushort_t WphiH[64 * 193];  // [k][j] = bf16(Wphi[j][k]), padded
    const int t = threadIdx.x;
    for (int i = t; i < 64 * 64; i += 256) {
        int j = i >> 6, k = i & 63;
        WsT[k * 65 + j] = Ws[i];
    }
    for (int i = t; i < 192 * 64; i += 256) {
        int j = i >> 6, k = i & 63;
        WphiH[k * 193 + j] = f2bf(Wphi[i]);
    }
    __syncthreads();

    const int lane = t & 63;
    const int wave = t >> 6;
    const int gw = blockIdx.x * 4 + wave;
    const int nw = gridDim.x * 4;
    const float bsc = bs[lane];
    const float bp0 = bphi[lane], bp1 = bphi[64 + lane], bp2 = bphi[128 + lane];

    for (int n0 = gw * MNODE; n0 < n_nodes; n0 += nw * MNODE) {
        const int cnt = min(MNODE, n_nodes - n0);
        float x[MNODE];
#pragma unroll
        for (int m = 0; m < MNODE; m++)
            x[m] = (m < cnt) ? node[(size_t)(n0 + m) * 64 + lane] : 0.f;

        float acc[MNODE];
#pragma unroll
        for (int m = 0; m < MNODE; m++) acc[m] = bsc;
#pragma unroll
        for (int k = 0; k < 64; k++) {
            float wv = WsT[k * 65 + lane];
#pragma unroll
            for (int m = 0; m < MNODE; m++) acc[m] += rdlane(x[m], k) * wv;
        }
        float s1[MNODE];
#pragma unroll
        for (int m = 0; m < MNODE; m++) {
            float a = acc[m];
            s1[m] = a / (1.f + __expf(-a));
        }
        float a0[MNODE], a1[MNODE], a2[MNODE];
#pragma unroll
        for (int m = 0; m < MNODE; m++) { a0[m] = bp0; a1[m] = bp1; a2[m] = bp2; }
#pragma unroll
        for (int k = 0; k < 64; k++) {
            float w0 = bf2f(WphiH[k * 193 + lane]);
            float w1 = bf2f(WphiH[k * 193 + 64 + lane]);
            float w2 = bf2f(WphiH[k * 193 + 128 + lane]);
#pragma unroll
            for (int m = 0; m < MNODE; m++) {
                float sv = rdlane(s1[m], k);
                a0[m] += sv * w0;
                a1[m] += sv * w1;
                a2[m] += sv * w2;
            }
        }
#pragma unroll
        for (int m = 0; m < MNODE; m++) {
            if (m < cnt) {
                size_t ob = (size_t)(n0 + m) * 384 + lane * 6;
                *(uint_t*)(sq + ob) = pack2bf(a0[m], a1[m]);   // slots 0,1 (4B-aligned)
                sq[ob + 2] = f2bf(a2[m]);                       // slot 2
            }
        }
    }
}

// ---------------------------------------------------------------------------
// accum10 (round-11 verified, UNCHANGED): register-resident bf16 weights,
// rbf unpacked-f32 in LDS, 12B fused gather with depth-1 prefetch.
// ---------------------------------------------------------------------------
__global__ __launch_bounds__(256, 4)
void accum10_kernel(const ushort_t* __restrict__ sq,
                    const uint4* __restrict__ rec,
                    const uint_t* __restrict__ wpkp,
                    const float* __restrict__ bw,
                    float* __restrict__ ds, float* __restrict__ dv, int n_edges)
{
    __shared__ int    sh_dst[4 * 64];
    __shared__ int    sh_src[4 * 64];
    __shared__ float  sh_env[4 * 64];
    __shared__ float  sh_r[4 * 3 * 64];            // [w][comp][edge]
    __shared__ float4 sh_rbf[4 * 64 * 5];          // [w][edge][q] unpacked f32

    const int lane = threadIdx.x & 63;
    const int w = threadIdx.x >> 6;
    const int tile = blockIdx.x * 4 + w;
    const int base = tile * 64;
    const int nvalid = min(64, n_edges - base);
    const int woff = w * 64;

    // ---- all 60 weights for this lane: 30 packed u32, register-resident ----
    uint_t wp[30];
#pragma unroll
    for (int i = 0; i < 30; i++) wp[i] = wpkp[i * 64 + lane];

    // ---- Phase 1: lane = edge, unpack 64B record ----
    if (lane < nvalid) {
        size_t rp = (size_t)(base + lane) * 4;
        uint4 qa = rec[rp], qb = rec[rp + 1], qc = rec[rp + 2], qd = rec[rp + 3];
        sh_src[woff + lane] = (int)qa.x;
        sh_dst[woff + lane] = (int)qa.y;
        sh_env[woff + lane] = __uint_as_float(qa.z);
        sh_r[w * 192 + lane]       = __uint_as_float(qa.w);
        sh_r[w * 192 + 64 + lane]  = __uint_as_float(qb.x);
        sh_r[w * 192 + 128 + lane] = __uint_as_float(qb.y);
        float4* dstq = &sh_rbf[(woff + lane) * 5];
        dstq[0] = make_float4(bflo(qb.z), bfhi(qb.z), bflo(qb.w), bfhi(qb.w));
        dstq[1] = make_float4(bflo(qc.x), bfhi(qc.x), bflo(qc.y), bfhi(qc.y));
        dstq[2] = make_float4(bflo(qc.z), bfhi(qc.z), bflo(qc.w), bfhi(qc.w));
        dstq[3] = make_float4(bflo(qd.x), bfhi(qd.x), bflo(qd.y), bfhi(qd.y));
        dstq[4] = make_float4(bflo(qd.z), bfhi(qd.z), bflo(qd.w), bfhi(qd.w));
    }
    __syncthreads();

    if (nvalid <= 0) return;

    const float bw0 = bw[lane], bw1 = bw[64 + lane], bw2 = bw[128 + lane];

    float a0 = 0.f, a1 = 0.f, a2 = 0.f, a3 = 0.f;
    int cur = sh_dst[woff];

    // prefetch edge 0's gather
    U3 gcur = *(const U3*)(sq + (size_t)sh_src[woff] * 384 + lane * 6);

    // ---- Phase 2: lane = channel ----
    for (int j = 0; j < nvalid; j++) {
        int jn = (j + 1 < nvalid) ? j + 1 : j;
        U3 gnxt = *(const U3*)(sq + (size_t)sh_src[woff + jn] * 384 + lane * 6);

        float ev = sh_env[woff + j];
        float r0 = sh_r[w * 192 + j];
        float r1 = sh_r[w * 192 + 64 + j];
        float r2 = sh_r[w * 192 + 128 + j];

        float sv0 = bflo(gcur.a);
        float sv1 = bfhi(gcur.a);
        float sv2 = bflo(gcur.b);
        float v0  = bfhi(gcur.b);
        float v1  = bflo(gcur.c);
        float v2  = bfhi(gcur.c);

        float w0 = bw0, w1 = bw1, w2 = bw2;
#pragma unroll
        for (int q = 0; q < 5; q++) {
            float4 rb = sh_rbf[(woff + j) * 5 + q];
            uint_t wa0 = wp[2 * q],      wa1 = wp[2 * q + 1];       // c=0
            uint_t wb0 = wp[10 + 2 * q], wb1 = wp[11 + 2 * q];      // c=1
            uint_t wc0 = wp[20 + 2 * q], wc1 = wp[21 + 2 * q];      // c=2
            w0 += rb.x * bflo(wa0) + rb.y * bfhi(wa0) + rb.z * bflo(wa1) + rb.w * bfhi(wa1);
            w1 += rb.x * bflo(wb0) + rb.y * bfhi(wb0) + rb.z * bflo(wb1) + rb.w * bfhi(wb1);
            w2 += rb.x * bflo(wc0) + rb.y * bfhi(wc0) + rb.z * bflo(wc1) + rb.w * bfhi(wc1);
        }
        w0 *= ev; w1 *= ev; w2 *= ev;

        float sw1 = sv1 * w1;
        float sw2 = sv2 * w2;
        a0 += sv0 * w0;
        a1 += v0 * sw1 + r0 * sw2;
        a2 += v1 * sw1 + r1 * sw2;
        a3 += v2 * sw1 + r2 * sw2;

        int nd = (j + 1 < nvalid) ? sh_dst[woff + j + 1] : -2;
        if (nd != cur) {
            unsafeAtomicAdd(&ds[(size_t)cur * 64 + lane], a0);
            size_t db = (size_t)cur * 192 + lane;
            unsafeAtomicAdd(&dv[db], a1);
            unsafeAtomicAdd(&dv[db + 64], a2);
            unsafeAtomicAdd(&dv[db + 128], a3);
            a0 = a1 = a2 = a3 = 0.f;
            cur = nd;
        }
        gcur = gnxt;
    }
}

// ===========================================================================
// T3 fallback (round-1, proven): row-major f32 s + atomic scatter.
// ===========================================================================
__global__ __launch_bounds__(256, 2)
void node_mlp_kernel(const float* __restrict__ node,
                     const float* __restrict__ Ws,
                     const float* __restrict__ bs,
                     const float* __restrict__ Wphi,
                     const float* __restrict__ bphi,
                     float* __restrict__ s_out,
                     int n_nodes)
{
    __shared__ float WsT[64 * 65];
    __shared__ float WphiT[64 * 193];
    const int t = threadIdx.x;
    for (int i = t; i < 64 * 64; i += 256) {
        int c = i >> 6, k = i & 63;
        WsT[k * 65 + c] = Ws[i];
    }
    for (int i = t; i < 192 * 64; i += 256) {
        int j = i >> 6, k = i & 63;
        WphiT[k * 193 + j] = Wphi[i];
    }
    __syncthreads();

    const int lane = t & 63;
    const int wave = t >> 6;
    const int nwaves = (gridDim.x * blockDim.x) >> 6;
    const float bsc = bs[lane];
    const float bp0 = bphi[lane], bp1 = bphi[64 + lane], bp2 = bphi[128 + lane];

    for (int n = blockIdx.x * 4 + wave; n < n_nodes; n += nwaves) {
        float x = node[(size_t)n * 64 + lane];
        float acc = bsc;
#pragma unroll
        for (int k = 0; k < 64; k++) acc += __shfl(x, k) * WsT[k * 65 + lane];
        float s1 = acc / (1.0f + __expf(-acc));
        float a0 = bp0, a1 = bp1, a2 = bp2;
#pragma unroll
        for (int k = 0; k < 64; k++) {
            float sk = __shfl(s1, k);
            a0 += sk * WphiT[k * 193 + lane];
            a1 += sk * WphiT[k * 193 + 64 + lane];
            a2 += sk * WphiT[k * 193 + 128 + lane];
        }
        size_t ob = (size_t)n * 192;
        s_out[ob + lane] = a0;
        s_out[ob + 64 + lane] = a1;
        s_out[ob + 128 + lane] = a2;
    }
}

__global__ __launch_bounds__(256)
void edge_kernel(const float* __restrict__ s,
                 const float* __restrict__ eq,
                 const float* __restrict__ rbf,
                 const float* __restrict__ env,
                 const float* __restrict__ rij,
                 const int* __restrict__ eidx,
                 const int* __restrict__ idx_flag,
                 const float* __restrict__ Ww,
                 const float* __restrict__ bw,
                 float* __restrict__ ds,
                 float* __restrict__ dv,
                 int n_edges)
{
    const int lane = threadIdx.x & 63;
    const int wglob = (blockIdx.x * blockDim.x + threadIdx.x) >> 6;
    const int nw = (gridDim.x * blockDim.x) >> 6;

    float ww0[NRAD], ww1[NRAD], ww2[NRAD];
#pragma unroll
    for (int k = 0; k < NRAD; k++) {
        ww0[k] = Ww[lane * NRAD + k];
        ww1[k] = Ww[(64 + lane) * NRAD + k];
        ww2[k] = Ww[(128 + lane) * NRAD + k];
    }
    const float bw0 = bw[lane], bw1 = bw[64 + lane], bw2 = bw[128 + lane];
    const int fmt32 = idx_flag[0];

    for (int e = wglob; e < n_edges; e += nw) {
        int dst, src;
        if (fmt32) {
            dst = eidx[2 * e];
            src = eidx[2 * e + 1];
        } else {
            const long long* e64 = (const long long*)eidx;
            dst = (int)e64[2 * e];
            src = (int)e64[2 * e + 1];
        }
        float ev = env[e];
        float r0 = rij[3 * e], r1 = rij[3 * e + 1], r2 = rij[3 * e + 2];
        float rb[NRAD];
#pragma unroll
        for (int k = 0; k < NRAD; k++) rb[k] = rbf[(size_t)e * NRAD + k];
        float w0 = bw0, w1 = bw1, w2 = bw2;
#pragma unroll
        for (int k = 0; k < NRAD; k++) {
            w0 += rb[k] * ww0[k];
            w1 += rb[k] * ww1[k];
            w2 += rb[k] * ww2[k];
        }
        w0 *= ev; w1 *= ev; w2 *= ev;

        size_t sb = (size_t)src * 192;
        float sw0 = s[sb + lane] * w0;
        float sw1 = s[sb + 64 + lane] * w1;
        float sw2 = s[sb + 128 + lane] * w2;
        float v0 = eq[sb + lane];
        float v1 = eq[sb + 64 + lane];
        float v2 = eq[sb + 128 + lane];

        unsafeAtomicAdd(&ds[(size_t)dst * 64 + lane], sw0);
        size_t db = (size_t)dst * 192;
        unsafeAtomicAdd(&dv[db + lane],       v0 * sw1 + r0 * sw2);
        unsafeAtomicAdd(&dv[db + 64 + lane],  v1 * sw1 + r1 * sw2);
        unsafeAtomicAdd(&dv[db + 128 + lane], v2 * sw1 + r2 * sw2);
    }
}

extern "C" void kernel_launch(void* const* d_in, const int* in_sizes, int n_in,
                              void* d_out, int out_size, void* d_ws, size_t ws_size,
                              hipStream_t stream)
{
    const float* node = (const float*)d_in[0];
    const float* eq   = (const float*)d_in[1];
    const float* rbf  = (const float*)d_in[2];
    const float* env  = (const float*)d_in[3];
    const float* rij  = (const float*)d_in[4];
    const int*   eidx = (const int*)d_in[5];
    const float* Ws   = (const float*)d_in[6];
    const float* bs   = (const float*)d_in[7];
    const float* Wphi = (const float*)d_in[8];
    const float* bphi = (const float*)d_in[9];
    const float* Ww   = (const float*)d_in[10];
    const float* bw   = (const float*)d_in[11];

    const int n_nodes = in_sizes[0] / 64;
    const int n_edges = in_sizes[3];

    float* out = (float*)d_out;
    float* ds = out;
    float* dv = out + (size_t)n_nodes * 64;
    char* ws = (char*)d_ws;

    const int ch = (n_nodes + 255) / 256;
    const int nb = (n_nodes + ch - 1) / ch;

    // ---- Tier-1 layout: interleaved sq[node][64][6] bf16 + 64B records ----
    {
        size_t off = 0;
        auto alloc = [&](size_t bytes) { size_t o = off; off = (off + bytes + 255) & ~(size_t)255; return o; };
        size_t o_sq   = alloc((size_t)n_nodes * 384 * sizeof(ushort_t));  // 6 ch interleaved
        size_t o_cnt  = alloc(2 * (size_t)n_nodes * sizeof(int));         // counts + cur
        size_t o_rec  = alloc((size_t)n_edges * 64);
        size_t o_wpk  = alloc(1920 * sizeof(uint_t));
        size_t o_bsum = alloc(512 * sizeof(int));
        size_t o_flag = alloc(16);
        if (ws_size >= off) {
            ushort_t* sq = (ushort_t*)(ws + o_sq);
            int* counts = (int*)(ws + o_cnt);
            int* cur = counts + n_nodes;
            uint4* rec = (uint4*)(ws + o_rec);
            uint_t* wpkp = (uint_t*)(ws + o_wpk);
            int* bsum = (int*)(ws + o_bsum);
            int* bscan = bsum + 256;
            int* flag = (int*)(ws + o_flag);

            hipMemsetAsync(counts, 0, (size_t)n_nodes * sizeof(int), stream);
            hipMemsetAsync(d_out, 0, (size_t)out_size * sizeof(float), stream);
            detect_idx_kernel<<<1, 64, 0, stream>>>(eidx, flag);
            prep_wpkp_kernel<<<8, 256, 0, stream>>>(Ww, wpkp);
            hist_kernel<<<1024, 256, 0, stream>>>(eidx, flag, counts, n_edges);
            scan1_kernel<<<nb, 256, 0, stream>>>(counts, bsum, n_nodes, ch);
            scan2_kernel<<<1, 256, 0, stream>>>(bsum, bscan, nb);
            scan3_kernel<<<nb, 256, 0, stream>>>(counts, bscan, cur, n_nodes, ch);
            scatter_rec_kernel<<<1024, 256, 0, stream>>>(eidx, flag, cur, env, rij, rbf,
                                                         rec, n_edges);
            eq_cast_i2_kernel<<<1024, 256, 0, stream>>>(eq, sq, n_nodes);
            node_mlp3j<<<512, 256, 0, stream>>>(node, Ws, bs, Wphi, bphi, sq, n_nodes);
            const int n_tiles = (n_edges + 63) / 64;
            accum10_kernel<<<(n_tiles + 3) / 4, 256, 0, stream>>>(
                sq, rec, wpkp, bw, ds, dv, n_edges);
            return;
        }
    }

    // ---- Tier-3: round-1 fallback (simple, fits any workspace >= s buffer) ----
    {
        float* s_ws = (float*)d_ws;
        int* idx_flag = (int*)(ws + (size_t)n_nodes * 192 * sizeof(float));
        hipMemsetAsync(d_out, 0, (size_t)out_size * sizeof(float), stream);
        detect_idx_kernel<<<1, 64, 0, stream>>>(eidx, idx_flag);
        node_mlp_kernel<<<1024, 256, 0, stream>>>(node, Ws, bs, Wphi, bphi, s_ws, n_nodes);
        edge_kernel<<<4096, 256, 0, stream>>>(s_ws, eq, rbf, env, rij, eidx, idx_flag,
                                              Ww, bw, ds, dv, n_edges);
    }
}